// Round 1
// baseline (127.583 us; speedup 1.0000x reference)
//
#include <hip/hip_runtime.h>

// Problem: left/right [2,32,64,128] f32, MAXDISP=192 (D=48 coarse) -> out [2,256,512]
#define BB 2
#define CC 32
#define HC 64
#define WC 128
#define HO 256
#define WO 512
#define MAXD 192
#define NBLK (BB * HO)        // 512 blocks, one per output row
#define RPAD 47               // zero pad in front of Rh
#define RSZ  176              // 47 zeros + 128 values + 1 zero guard (w0=127,t[-1])

// dd -> coarse segment walk. t[d] = Rq[47-d] where Rq = &Rhp[w0], zero-padded so
// t[d] = (w0>=d) ? Rh[w0-d] : 0.  vv[d] = base(d) + c0*t[d] + c1*t[d-1].
// base(d): cA for d<=w0; c1*lw1 at d==w0+1; 0 beyond. Clean waves (all w0>=47): cA always.
// All values pre-scaled by log2(e)/64 so v_exp_f32 (exp2) applies directly.
// Within segment d, wd steps by KD -> chain e *= exp2(s*KD): 2 exps per segment.
template <bool MASKED>
__device__ __forceinline__ float2 dd_sweep(const float* Rq,
                                           float c0, float c1, float cA,
                                           float cB0, float cB1, float fw0) {
    const float KD = 47.0f / 191.0f;
    float tc  = Rq[RPAD];         // t[0]
    float tmm = Rq[RPAD + 1];     // t[-1] (guard slot when w0==127; c1==0 there)
    float vvc = fmaf(c0, tc, fmaf(c1, tmm, cA));   // base(0)==cA always (d=0<=w0)
    float tn = 0.f, vvn = 0.f, s = 0.f, e = 0.f, rr = 1.f;
    float ls = 0.f, ss = 0.f;
#pragma unroll
    for (int dd = 0; dd < MAXD; ++dd) {
        const int d = (dd * 47) / 191;                               // compile-time
        const bool segstart = (dd == 0) || (d != (((dd - 1) * 47) / 191));
        if (segstart) {
            if (dd != 0) { vvc = vvn; tc = tn; }
            if (d < 47) {
                tn = Rq[RPAD - d - 1];                               // t[d+1]
                float bn;
                if (MASKED) {
                    float fd = (float)(d + 1);
                    bn = fmaf(cB0, __saturatef(fw0 - fd + 1.f),
                              cB1 * __saturatef(fw0 - fd + 2.f));
                } else {
                    bn = cA;
                }
                vvn = fmaf(c0, tn, fmaf(c1, tc, bn));
                s = vvn - vvc;
            } else {
                s = 0.f;        // dd==191: wd==0, vv[48] never weighted
            }
            const float wdf = (float)dd * KD - (float)d;             // compile-time
            e  = __builtin_amdgcn_exp2f(fmaf(wdf, s, vvc));
            rr = __builtin_amdgcn_exp2f(s * KD);
        }
        ls += e;
        ss = fmaf(e, (float)dd, ss);
        e *= rr;
    }
    return make_float2(ls, ss);
}

__global__ __launch_bounds__(512, 4) void fused_disp_kernel(
    const float* __restrict__ left, const float* __restrict__ right,
    float* __restrict__ out) {
    __shared__ float4 red[2][8][32];   // [mat][channel-group][w-quad]
    __shared__ float  Lh[WC];
    __shared__ float  Rhp[RSZ];

    // XCD-contiguous bijective swizzle: 512 blocks, 8 XCDs, 64 consecutive rows/XCD.
    int blk = blockIdx.x;
    int r   = (blk & 7) * (NBLK / 8) + (blk >> 3);
    int b   = r >> 8;
    int hh  = r & (HO - 1);

    float src_h = (float)hh * (63.0f / 255.0f);
    int h0 = (int)src_h; if (h0 > HC - 1) h0 = HC - 1;
    int h1 = h0 + 1;     if (h1 > HC - 1) h1 = HC - 1;
    float fh = src_h - (float)h0;

    int t = threadIdx.x;

    // ---- Phase 0: fused channel-sum (32 ch) + fh row blend, float4 loads ----
    {
        int mat = t >> 8;          // 0=left 1=right
        int u   = t & 255;
        int cg  = u >> 5;          // 8 groups of 4 channels
        int wq  = u & 31;          // float4 quad in w
        const float* srcp = (mat ? right : left) + (size_t)b * (CC * HC * WC);
        float ax = 0.f, ay = 0.f, az = 0.f, aw = 0.f;
        float bx = 0.f, by = 0.f, bz = 0.f, bw = 0.f;
#pragma unroll
        for (int i = 0; i < 4; ++i) {
            int c = cg * 4 + i;
            float4 v0 = *(const float4*)(srcp + ((c * HC + h0) * WC + wq * 4));
            float4 v1 = *(const float4*)(srcp + ((c * HC + h1) * WC + wq * 4));
            ax += v0.x; ay += v0.y; az += v0.z; aw += v0.w;
            bx += v1.x; by += v1.y; bz += v1.z; bw += v1.w;
        }
        float gh = 1.f - fh;
        red[mat][cg][wq] = make_float4(fmaf(gh, ax, fh * bx), fmaf(gh, ay, fh * by),
                                       fmaf(gh, az, fh * bz), fmaf(gh, aw, fh * bw));
    }
    __syncthreads();
    // reduce the 8 channel-groups -> Lh[128] / Rhp[47..174]; zero the pads
    if (t < 256) {
        int mat = t >> 7;
        int w   = t & 127;
        const float* redf = (const float*)red;
        float s = 0.f;
#pragma unroll
        for (int cgi = 0; cgi < 8; ++cgi) s += redf[(mat * 8 + cgi) * 128 + w];
        if (mat == 0) Lh[w] = s;
        else          Rhp[RPAD + w] = s;
    } else {
        int z = t - 256;
        if (z < RPAD)       Rhp[z] = 0.f;        // leading zeros
        else if (z == RPAD) Rhp[RSZ - 1] = 0.f;  // t[-1] guard for w0==127
    }
    __syncthreads();

    // ---- Phase 2: one thread per output pixel, full 192-dd sweep ----
    int ww = t;
    float src_w = (float)ww * (127.0f / 511.0f);
    int w0 = (int)src_w; if (w0 > WC - 1) w0 = WC - 1;
    int w1 = w0 + 1;     if (w1 > WC - 1) w1 = WC - 1;
    float fw = src_w - (float)w0;

    const float L2E_SC = 1.4426950408889634f / 64.0f;  // log2(e) * (1/64 channel mean)
    float c0  = (1.f - fw) * L2E_SC;
    float c1  = fw * L2E_SC;
    float lw0 = Lh[w0], lw1 = Lh[w1];
    float cB0 = c0 * lw0, cB1 = c1 * lw1;
    float cA  = cB0 + cB1;
    float fw0 = (float)w0;
    const float* Rq = Rhp + w0;

    // waves 0..2 (px 0..191) can hit the mask boundary (w0 < 47); waves 3..7 never do.
    float2 acc = (t < 192) ? dd_sweep<true >(Rq, c0, c1, cA, cB0, cB1, fw0)
                           : dd_sweep<false>(Rq, c0, c1, cA, cB0, cB1, fw0);

    out[(size_t)(b * HO + hh) * WO + ww] = acc.y / acc.x;
}

extern "C" void kernel_launch(void* const* d_in, const int* in_sizes, int n_in,
                              void* d_out, int out_size, void* d_ws, size_t ws_size,
                              hipStream_t stream) {
    const float* left  = (const float*)d_in[0];
    const float* right = (const float*)d_in[1];
    fused_disp_kernel<<<NBLK, 512, 0, stream>>>(left, right, (float*)d_out);
}

// Round 2
// 65.963 us; speedup vs baseline: 1.9342x; 1.9342x over previous
//
#include <hip/hip_runtime.h>

// Problem: left/right [2,32,64,128] f32, MAXDISP=192 (D=48 coarse) -> out [2,256,512]
#define BB 2
#define CC 32
#define HC 64
#define WC 128
#define HO 256
#define WO 512
#define MAXD 192
#define NBLK (BB * HO)        // 512 blocks, one per output row
#define RPAD 47               // zero pad in front of Rh
#define RSZ  176              // 47 zeros + 128 values + 1 zero guard (w0=127, d=0)

// One dd-quarter: dd in [48K, 48K+47]. Coarse segment d = dd*47/191 (compile-time
// after unroll). vv[j] (d = DLO+j) = base(d) + c0*Rh[w0-d] + c1*Rh[w1-d], with the
// R terms' (w>=d) masks handled by the zero pad in Rhp, and the L-term mask either
// always-true (clean waves, w0>=47) or via saturate (masked waves, t<192).
// All coefficients pre-scaled by log2(e)/64 so v_exp_f32 (=exp2) applies directly.
#define QUARTER(K, MASKED)                                                     \
  {                                                                            \
    constexpr int DDLO = 48 * (K);                                             \
    constexpr int DLO  = (DDLO * 47) / 191;                                    \
    constexpr int DHI  = ((DDLO + 47) * 47) / 191;                             \
    constexpr int NV   = DHI - DLO + 2;                                        \
    float vv[NV];                                                              \
    _Pragma("unroll")                                                          \
    for (int j = 0; j < NV; ++j) {                                             \
      int d = DLO + j;                                                         \
      if (d > 47) {                                                            \
        vv[j] = vv[j - 1];              /* v[48] := v[47] (wd=0 there) */      \
      } else {                                                                 \
        float t0 = Rhp[RPAD + w0 - d];        /* Rh[w0-d], 0 if w0<d  */       \
        float t1 = Rhp[RPAD + w0 - d + 1];    /* Rh[w1-d], 0 if w1<d  */       \
        float bn;                                                              \
        if (MASKED) {                                                          \
          float df = (float)d;                                                 \
          bn = fmaf(cB0, __saturatef(w0f - df + 1.f),                          \
                    cB1 * __saturatef(w0f - df + 2.f));                        \
        } else {                                                               \
          bn = cA;                                                             \
        }                                                                      \
        vv[j] = fmaf(c0, t0, fmaf(c1, t1, bn));                                \
      }                                                                        \
    }                                                                          \
    _Pragma("unroll")                                                          \
    for (int dd = DDLO; dd < DDLO + 48; ++dd) {                                \
      int j = (dd * 47) / 191 - DLO;                                           \
      float wdf = (float)dd * (47.0f / 191.0f) - (float)((dd * 47) / 191);     \
      float x = fmaf(wdf, vv[j + 1] - vv[j], vv[j]);                           \
      float e = __builtin_amdgcn_exp2f(x);                                     \
      ls += e;                                                                 \
      ss = fmaf(e, (float)dd, ss);                                             \
    }                                                                          \
  }

__global__ __launch_bounds__(512)
__attribute__((amdgpu_waves_per_eu(4, 4)))
void fused_disp_kernel(const float* __restrict__ left,
                       const float* __restrict__ right,
                       float* __restrict__ out) {
    __shared__ float4 red[2][8][32];   // [mat][channel-group][w-quad]
    __shared__ float  Lh[WC];
    __shared__ float  Rhp[RSZ];

    // XCD-contiguous bijective swizzle: 512 blocks, 8 XCDs, 64 consecutive rows/XCD
    // -> per-XCD input working set ~0.6 MB (L2-resident).
    int blk = blockIdx.x;
    int r   = (blk & 7) * (NBLK / 8) + (blk >> 3);
    int b   = r >> 8;
    int hh  = r & (HO - 1);

    float src_h = (float)hh * (63.0f / 255.0f);
    int h0 = (int)src_h; if (h0 > HC - 1) h0 = HC - 1;
    int h1 = h0 + 1;     if (h1 > HC - 1) h1 = HC - 1;
    float fh = src_h - (float)h0;

    int t = threadIdx.x;

    // ---- Phase 0: fused channel-sum (32 ch) + fh row blend, float4 loads ----
    {
        int mat = t >> 8;          // 0=left 1=right
        int u   = t & 255;
        int cg  = u >> 5;          // 8 groups of 4 channels
        int wq  = u & 31;          // float4 quad in w
        const float* srcp = (mat ? right : left) + (size_t)b * (CC * HC * WC);
        float ax = 0.f, ay = 0.f, az = 0.f, aw = 0.f;
        float bx = 0.f, by = 0.f, bz = 0.f, bw = 0.f;
#pragma unroll
        for (int i = 0; i < 4; ++i) {
            int c = cg * 4 + i;
            float4 v0 = *(const float4*)(srcp + ((c * HC + h0) * WC + wq * 4));
            float4 v1 = *(const float4*)(srcp + ((c * HC + h1) * WC + wq * 4));
            ax += v0.x; ay += v0.y; az += v0.z; aw += v0.w;
            bx += v1.x; by += v1.y; bz += v1.z; bw += v1.w;
        }
        float gh = 1.f - fh;
        red[mat][cg][wq] = make_float4(fmaf(gh, ax, fh * bx), fmaf(gh, ay, fh * by),
                                       fmaf(gh, az, fh * bz), fmaf(gh, aw, fh * bw));
    }
    __syncthreads();
    // reduce the 8 channel-groups -> Lh[128] / Rhp[47..174]; zero the pads
    if (t < 256) {
        int mat = t >> 7;
        int w   = t & 127;
        const float* redf = (const float*)red;
        float s = 0.f;
#pragma unroll
        for (int cgi = 0; cgi < 8; ++cgi) s += redf[(mat * 8 + cgi) * 128 + w];
        if (mat == 0) Lh[w] = s;
        else          Rhp[RPAD + w] = s;
    } else {
        int z = t - 256;
        if (z < RPAD)       Rhp[z] = 0.f;        // leading zeros (R mask)
        else if (z == RPAD) Rhp[RSZ - 1] = 0.f;  // guard for w0==127, d==0
    }
    __syncthreads();

    // ---- Phase 2: one thread per output pixel, 192-dd sweep in 4 quarters ----
    int ww = t;
    float src_w = (float)ww * (127.0f / 511.0f);
    int w0 = (int)src_w; if (w0 > WC - 1) w0 = WC - 1;
    int w1 = w0 + 1;     if (w1 > WC - 1) w1 = WC - 1;
    float fw = src_w - (float)w0;

    const float L2E_SC = 1.4426950408889634f / 64.0f;  // log2(e) * (1/64 mean)
    float c0  = (1.f - fw) * L2E_SC;
    float c1  = fw * L2E_SC;
    float lw0 = Lh[w0], lw1 = Lh[w1];
    float cB0 = c0 * lw0, cB1 = c1 * lw1;
    float cA  = cB0 + cB1;
    float w0f = (float)w0;

    float ls = 0.f, ss = 0.f;
    if (t < 192) {              // waves 0..2: w0 can be < 47 -> masked base
        QUARTER(0, true)
        QUARTER(1, true)
        QUARTER(2, true)
        QUARTER(3, true)
    } else {                    // waves 3..7: w0 >= 47 -> base == cA always
        QUARTER(0, false)
        QUARTER(1, false)
        QUARTER(2, false)
        QUARTER(3, false)
    }

    out[(size_t)r * WO + ww] = ss / ls;
}

extern "C" void kernel_launch(void* const* d_in, const int* in_sizes, int n_in,
                              void* d_out, int out_size, void* d_ws, size_t ws_size,
                              hipStream_t stream) {
    const float* left  = (const float*)d_in[0];
    const float* right = (const float*)d_in[1];
    fused_disp_kernel<<<NBLK, 512, 0, stream>>>(left, right, (float*)d_out);
}

// Round 3
// 63.893 us; speedup vs baseline: 1.9968x; 1.0324x over previous
//
#include <hip/hip_runtime.h>

// Problem: left/right [2,32,64,128] f32, MAXDISP=192 (D=48 coarse) -> out [2,256,512]
#define BB 2
#define CC 32
#define HC 64
#define WC 128
#define HO 256
#define WO 512
#define MAXD 192
#define NBLK (BB * HO)        // 512 blocks, one per output row
#define RPAD 47               // zero pad in front of Rh
#define RSZ  176              // 47 zeros + 128 values + 1 zero guard (w0=127, d=0)

// One dd-quarter: dd in [48K, 48K+47]. Coarse segment d = dd*47/191. Per segment,
// vv[j] (d = DLO+j) = base(d) + c0*Rh[w0-d] + c1*Rh[w1-d]  (R masks via zero pad,
// L mask via saturate on masked waves). All coefficients pre-scaled by log2(e)/64.
// Within a segment the softmax argument is LINEAR in dd (step s*KD), so the exps
// form a geometric series: e_{k+1} = e_k * exp2(s*KD). Two v_exp_f32 per segment
// (~104 total) instead of one per dd (192). Chains are <=4 multiplies long.
// ls/ss split into parity accumulators to break the 192-long dependent add chain.
#define QUARTER(K, MASKED)                                                     \
  {                                                                            \
    constexpr int DDLO = 48 * (K);                                             \
    constexpr int DDHI = DDLO + 47;                                            \
    constexpr int DLO  = (DDLO * 47) / 191;                                    \
    constexpr int DHI  = (DDHI * 47) / 191;                                    \
    constexpr int NV   = DHI - DLO + 2;                                        \
    float vv[NV];                                                              \
    _Pragma("unroll")                                                          \
    for (int j = 0; j < NV; ++j) {                                             \
      int d = DLO + j;                                                         \
      if (d > 47) {                                                            \
        vv[j] = vv[j - 1];              /* v[48] := v[47] (wd=0 there) */      \
      } else {                                                                 \
        float t0 = Rhp[RPAD + w0 - d];        /* Rh[w0-d], 0 if w0<d  */       \
        float t1 = Rhp[RPAD + w0 - d + 1];    /* Rh[w1-d], 0 if w1<d  */       \
        float bn;                                                              \
        if (MASKED) {                                                          \
          float df = (float)d;                                                 \
          bn = fmaf(cB0, __saturatef(w0f - df + 1.f),                          \
                    cB1 * __saturatef(w0f - df + 2.f));                        \
        } else {                                                               \
          bn = cA;                                                             \
        }                                                                      \
        vv[j] = fmaf(c0, t0, fmaf(c1, t1, bn));                                \
      }                                                                        \
    }                                                                          \
    _Pragma("unroll")                                                          \
    for (int j = DLO; j <= DHI; ++j) {                                         \
      int dd0 = (191 * j + 46) / 47;  if (dd0 < DDLO) dd0 = DDLO;              \
      int dd1 = (191 * j + 190) / 47; if (dd1 > DDHI) dd1 = DDHI;              \
      float s   = vv[j - DLO + 1] - vv[j - DLO];                               \
      float wd0 = (float)dd0 * (47.0f / 191.0f) - (float)j;                    \
      float e   = __builtin_amdgcn_exp2f(fmaf(wd0, s, vv[j - DLO]));           \
      float rr  = 1.f;                                                         \
      if (dd1 > dd0) rr = __builtin_amdgcn_exp2f(s * (47.0f / 191.0f));        \
      _Pragma("unroll")                                                        \
      for (int dd = dd0; dd <= dd1; ++dd) {                                    \
        if (dd & 1) { ls1 += e; ss1 = fmaf(e, (float)dd, ss1); }               \
        else        { ls0 += e; ss0 = fmaf(e, (float)dd, ss0); }               \
        if (dd < dd1) e *= rr;                                                 \
      }                                                                        \
    }                                                                          \
  }

__global__ __launch_bounds__(512)
__attribute__((amdgpu_waves_per_eu(4, 4)))
void fused_disp_kernel(const float* __restrict__ left,
                       const float* __restrict__ right,
                       float* __restrict__ out) {
    __shared__ float4 red[2][8][32];   // [mat][channel-group][w-quad]
    __shared__ float  Lh[WC];
    __shared__ float  Rhp[RSZ];

    // XCD-contiguous bijective swizzle: 512 blocks, 8 XCDs, 64 consecutive rows/XCD
    // -> per-XCD input working set ~0.6 MB (L2-resident).
    int blk = blockIdx.x;
    int r   = (blk & 7) * (NBLK / 8) + (blk >> 3);
    int b   = r >> 8;
    int hh  = r & (HO - 1);

    float src_h = (float)hh * (63.0f / 255.0f);
    int h0 = (int)src_h; if (h0 > HC - 1) h0 = HC - 1;
    int h1 = h0 + 1;     if (h1 > HC - 1) h1 = HC - 1;
    float fh = src_h - (float)h0;

    int t = threadIdx.x;

    // ---- Phase 0: fused channel-sum (32 ch) + fh row blend, float4 loads ----
    {
        int mat = t >> 8;          // 0=left 1=right
        int u   = t & 255;
        int cg  = u >> 5;          // 8 groups of 4 channels
        int wq  = u & 31;          // float4 quad in w
        const float* srcp = (mat ? right : left) + (size_t)b * (CC * HC * WC);
        float ax = 0.f, ay = 0.f, az = 0.f, aw = 0.f;
        float bx = 0.f, by = 0.f, bz = 0.f, bw = 0.f;
#pragma unroll
        for (int i = 0; i < 4; ++i) {
            int c = cg * 4 + i;
            float4 v0 = *(const float4*)(srcp + ((c * HC + h0) * WC + wq * 4));
            float4 v1 = *(const float4*)(srcp + ((c * HC + h1) * WC + wq * 4));
            ax += v0.x; ay += v0.y; az += v0.z; aw += v0.w;
            bx += v1.x; by += v1.y; bz += v1.z; bw += v1.w;
        }
        float gh = 1.f - fh;
        red[mat][cg][wq] = make_float4(fmaf(gh, ax, fh * bx), fmaf(gh, ay, fh * by),
                                       fmaf(gh, az, fh * bz), fmaf(gh, aw, fh * bw));
    }
    __syncthreads();
    // reduce the 8 channel-groups -> Lh[128] / Rhp[47..174]; zero the pads
    if (t < 256) {
        int mat = t >> 7;
        int w   = t & 127;
        const float* redf = (const float*)red;
        float s = 0.f;
#pragma unroll
        for (int cgi = 0; cgi < 8; ++cgi) s += redf[(mat * 8 + cgi) * 128 + w];
        if (mat == 0) Lh[w] = s;
        else          Rhp[RPAD + w] = s;
    } else {
        int z = t - 256;
        if (z < RPAD)       Rhp[z] = 0.f;        // leading zeros (R mask)
        else if (z == RPAD) Rhp[RSZ - 1] = 0.f;  // guard for w0==127, d==0
    }
    __syncthreads();

    // ---- Phase 2: one thread per output pixel, 192-dd sweep in 4 quarters ----
    int ww = t;
    float src_w = (float)ww * (127.0f / 511.0f);
    int w0 = (int)src_w; if (w0 > WC - 1) w0 = WC - 1;
    int w1 = w0 + 1;     if (w1 > WC - 1) w1 = WC - 1;
    float fw = src_w - (float)w0;

    const float L2E_SC = 1.4426950408889634f / 64.0f;  // log2(e) * (1/64 mean)
    float c0  = (1.f - fw) * L2E_SC;
    float c1  = fw * L2E_SC;
    float lw0 = Lh[w0], lw1 = Lh[w1];
    float cB0 = c0 * lw0, cB1 = c1 * lw1;
    float cA  = cB0 + cB1;
    float w0f = (float)w0;

    float ls0 = 0.f, ls1 = 0.f, ss0 = 0.f, ss1 = 0.f;
    if (t < 192) {              // waves 0..2: w0 can be < 47 -> masked base
        QUARTER(0, true)
        QUARTER(1, true)
        QUARTER(2, true)
        QUARTER(3, true)
    } else {                    // waves 3..7: w0 >= 47 -> base == cA always
        QUARTER(0, false)
        QUARTER(1, false)
        QUARTER(2, false)
        QUARTER(3, false)
    }

    out[(size_t)r * WO + ww] = (ss0 + ss1) / (ls0 + ls1);
}

extern "C" void kernel_launch(void* const* d_in, const int* in_sizes, int n_in,
                              void* d_out, int out_size, void* d_ws, size_t ws_size,
                              hipStream_t stream) {
    const float* left  = (const float*)d_in[0];
    const float* right = (const float*)d_in[1];
    fused_disp_kernel<<<NBLK, 512, 0, stream>>>(left, right, (float*)d_out);
}